// Round 1
// baseline (576.433 us; speedup 1.0000x reference)
//
#include <hip/hip_runtime.h>
#include <stdint.h>

// ---------- types ----------
typedef __attribute__((ext_vector_type(8))) short  short8;   // 8 bf16 (4 VGPRs)
typedef __attribute__((ext_vector_type(4))) float  f32x4;
typedef __attribute__((ext_vector_type(4))) float  float4v;
typedef __attribute__((ext_vector_type(4))) unsigned short ushort4v;

#define DEV __device__ __forceinline__

// ---------- bf16 helpers (RNE) ----------
DEV unsigned short f2bf(float f) {
    union { float f; unsigned int u; } x; x.f = f;
    unsigned int u = x.u;
    unsigned int r = (u + 0x7fffu + ((u >> 16) & 1u)) >> 16;
    return (unsigned short)r;
}
DEV float bf2f(unsigned short b) {
    union { unsigned int u; float f; } x; x.u = ((unsigned int)b) << 16;
    return x.f;
}

// ---------- async global->LDS, 16B/lane ----------
DEV void gll16(const void* g, void* l) {
    __builtin_amdgcn_global_load_lds(
        (const __attribute__((address_space(1))) void*)g,
        (__attribute__((address_space(3))) void*)l, 16, 0, 0);
}

// ---------- problem constants ----------
// B=4 T=1024 DIM=2048 H=16 HD=HDE=128 ; M = B*T = 4096
#define MROWS 4096
#define KDIM  2048
#define NQK   4096

// ============================================================
// elementwise f32 -> bf16 cast (vectorized float4 -> 4x bf16)
// ============================================================
__global__ void cast_f32_bf16(const float* __restrict__ in,
                              unsigned short* __restrict__ out, int n4) {
    int i = blockIdx.x * blockDim.x + threadIdx.x;
    if (i < n4) {
        float4v f = ((const float4v*)in)[i];
        ushort4v o;
        o[0] = f2bf(f[0]); o[1] = f2bf(f[1]); o[2] = f2bf(f[2]); o[3] = f2bf(f[3]);
        ((ushort4v*)out)[i] = o;
    }
}

// ============================================================
// transpose + cast: W (K x N, f32) -> Wt (N x K, bf16)
// 32x32 LDS tile, block (32,8)
// ============================================================
__global__ void transpose_cast(const float* __restrict__ W,
                               unsigned short* __restrict__ Wt, int K, int N) {
    __shared__ float tile[32][33];
    int tx = threadIdx.x, ty = threadIdx.y;
    int n0 = blockIdx.x * 32, k0 = blockIdx.y * 32;
#pragma unroll
    for (int j = 0; j < 32; j += 8)
        tile[ty + j][tx] = W[(size_t)(k0 + ty + j) * N + n0 + tx];
    __syncthreads();
#pragma unroll
    for (int j = 0; j < 32; j += 8)
        Wt[(size_t)(n0 + ty + j) * K + k0 + tx] = f2bf(tile[tx][ty + j]);
}

// ============================================================
// GEMM  C[M x N] = A[M x K] * Bt[N x K]^T   (both bf16, acc f32)
// 128x128 tile, 4 waves (2x2), BK=32, mfma_f32_16x16x32_bf16
// OUTBF: write bf16 to C16, else f32 to Cf
// ============================================================
template <bool OUTBF>
__global__ __launch_bounds__(256) void gemm_bt(
    const unsigned short* __restrict__ A,
    const unsigned short* __restrict__ Bt,
    float* __restrict__ Cf, unsigned short* __restrict__ C16,
    int M, int N, int K) {

    __shared__ __align__(16) unsigned short As[128 * 32];
    __shared__ __align__(16) unsigned short Bs[128 * 32];

    const int tid  = threadIdx.x;
    const int w    = tid >> 6;
    const int lane = tid & 63;
    const int lr   = lane & 15;
    const int lk   = lane >> 4;
    const int wr   = w >> 1, wc = w & 1;
    const int rowBase = blockIdx.y * 128;
    const int colBase = blockIdx.x * 128;

    f32x4 acc[4][4];
#pragma unroll
    for (int m = 0; m < 4; ++m)
#pragma unroll
        for (int n = 0; n < 4; ++n)
            acc[m][n] = (f32x4){0.f, 0.f, 0.f, 0.f};

    for (int k0 = 0; k0 < K; k0 += 32) {
        // stage A tile [128][32] and Bt tile [128][32] (linear, lane-order)
#pragma unroll
        for (int r = 0; r < 2; ++r) {
            int E   = r * 2048 + tid * 8;
            int row = E >> 5, col = E & 31;
            gll16(A  + (size_t)(rowBase + row) * K + k0 + col, &As[r * 2048 + w * 512]);
            gll16(Bt + (size_t)(colBase + row) * K + k0 + col, &Bs[r * 2048 + w * 512]);
        }
        __syncthreads();

        short8 a[4], b[4];
#pragma unroll
        for (int m = 0; m < 4; ++m)
            a[m] = *(const short8*)&As[(wr * 64 + m * 16 + lr) * 32 + lk * 8];
#pragma unroll
        for (int n = 0; n < 4; ++n)
            b[n] = *(const short8*)&Bs[(wc * 64 + n * 16 + lr) * 32 + lk * 8];
#pragma unroll
        for (int m = 0; m < 4; ++m)
#pragma unroll
            for (int n = 0; n < 4; ++n)
                acc[m][n] = __builtin_amdgcn_mfma_f32_16x16x32_bf16(a[m], b[n], acc[m][n], 0, 0, 0);
        __syncthreads();
    }

    // epilogue: C/D layout col = lane&15, row = (lane>>4)*4 + reg
#pragma unroll
    for (int m = 0; m < 4; ++m)
#pragma unroll
        for (int n = 0; n < 4; ++n)
#pragma unroll
            for (int r = 0; r < 4; ++r) {
                int row = rowBase + wr * 64 + m * 16 + lk * 4 + r;
                int col = colBase + wc * 64 + n * 16 + lr;
                float v = acc[m][n][r];
                if (OUTBF) C16[(size_t)row * N + col] = f2bf(v);
                else       Cf [(size_t)row * N + col] = v;
            }
}

// ============================================================
// RoPE in-place on qk16 (4096 rows x 4096 cols bf16).
// cols [0,2048) = q, [2048,4096) = k ; per head 128 dims = 64 pairs.
// Each thread: 4 pairs (8 bf16, one short8).
// ============================================================
__global__ void rope_kernel(unsigned short* __restrict__ qk,
                            const float* __restrict__ fcos,
                            const float* __restrict__ fsin) {
    int idx  = blockIdx.x * 256 + threadIdx.x;   // 4096 rows * 512 groups
    int row  = idx >> 9;
    int g    = idx & 511;
    int t    = row & 1023;
    int half = g >> 8;
    int hp   = g & 255;
    int h    = hp >> 4;
    int ig   = hp & 15;
    int col  = half * 2048 + h * 128 + ig * 8;
    size_t off = (size_t)row * 4096 + col;

    short8 v = *(short8*)(qk + off);
    int i0 = ig * 4;
    float4v c = *(const float4v*)(fcos + t * 64 + i0);
    float4v s = *(const float4v*)(fsin + t * 64 + i0);
    short8 o;
#pragma unroll
    for (int p = 0; p < 4; ++p) {
        float re = bf2f((unsigned short)v[2 * p]);
        float im = bf2f((unsigned short)v[2 * p + 1]);
        o[2 * p]     = (short)f2bf(re * c[p] - im * s[p]);
        o[2 * p + 1] = (short)f2bf(re * s[p] + im * c[p]);
    }
    *(short8*)(qk + off) = o;
}

// ============================================================
// Flash-style causal attention.
// grid = (16 q-tiles, 64 b*h), block = 256 (4 waves x 16 q-rows).
// Q rows in regs; K tile [64][128] linear LDS (gll);
// V tile transposed [128][64]; P via padded LDS (stride 72).
// ============================================================
__global__ __launch_bounds__(256) void attn_kernel(
    const unsigned short* __restrict__ qk,   // 4096 x 4096 (q | k), roped
    const unsigned short* __restrict__ vp,   // 4096 x 2048
    unsigned short* __restrict__ y) {        // 4096 x 2048

    int qt = blockIdx.x;          // 0..15
    int bh = blockIdx.y;          // 0..63
    int b = bh >> 4, h = bh & 15;

    __shared__ __align__(16) unsigned short Kt[64 * 128];  // [t][d]
    __shared__ __align__(16) unsigned short Vt[128 * 64];  // [d][t]
    __shared__ __align__(16) unsigned short Pl[4 * 16 * 72];

    const int tid = threadIdx.x, w = tid >> 6, lane = tid & 63;
    const int lr = lane & 15, lk = lane >> 4;

    const unsigned short* Qb = qk + (size_t)(b * 1024) * 4096 + h * 128;
    const unsigned short* Kb = Qb + 2048;
    const unsigned short* Vb = vp + (size_t)(b * 1024) * 2048 + h * 128;
    unsigned short* Pw = &Pl[w * 16 * 72];

    // Q fragments: rows qt*64 + w*16 + lr, d = db*32 + lk*8
    short8 qf[4];
    {
        const unsigned short* qrow = Qb + (size_t)(qt * 64 + w * 16 + lr) * 4096;
#pragma unroll
        for (int db = 0; db < 4; ++db)
            qf[db] = *(const short8*)(qrow + db * 32 + lk * 8);
    }

    f32x4 acc[8];
#pragma unroll
    for (int n = 0; n < 8; ++n) acc[n] = (f32x4){0.f, 0.f, 0.f, 0.f};
    float m_i[4] = {-1e30f, -1e30f, -1e30f, -1e30f};
    float l_i[4] = {0.f, 0.f, 0.f, 0.f};

    for (int kt = 0; kt <= qt; ++kt) {
        // --- stage K tile (linear, gll 16B) ---
#pragma unroll
        for (int r = 0; r < 4; ++r) {
            int E = r * 2048 + tid * 8;
            int tr = E >> 7, col = E & 127;
            gll16(Kb + (size_t)(kt * 64 + tr) * 4096 + col, &Kt[r * 2048 + w * 512]);
        }
        // --- stage V transposed ---
#pragma unroll
        for (int it = 0; it < 4; ++it) {
            int idx = it * 256 + tid;
            int tv = idx >> 4, d0 = (idx & 15) * 8;
            short8 vv = *(const short8*)(Vb + (size_t)(kt * 64 + tv) * 2048 + d0);
#pragma unroll
            for (int j = 0; j < 8; ++j)
                Vt[(d0 + j) * 64 + tv] = (unsigned short)vv[j];
        }
        __syncthreads();

        // --- S = Q K^T  (16 q-rows x 64 keys per wave) ---
        f32x4 s[4];
#pragma unroll
        for (int n = 0; n < 4; ++n) s[n] = (f32x4){0.f, 0.f, 0.f, 0.f};
#pragma unroll
        for (int db = 0; db < 4; ++db)
#pragma unroll
            for (int n = 0; n < 4; ++n) {
                short8 kf = *(const short8*)&Kt[(n * 16 + lr) * 128 + db * 32 + lk * 8];
                s[n] = __builtin_amdgcn_mfma_f32_16x16x32_bf16(qf[db], kf, s[n], 0, 0, 0);
            }

        // --- scale + causal mask ---
        const float sc = 0.08838834764831845f;   // 1/sqrt(128)
#pragma unroll
        for (int n = 0; n < 4; ++n)
#pragma unroll
            for (int r = 0; r < 4; ++r) {
                float v = s[n][r] * sc;
                if (kt == qt && (n * 16 + lr) > (w * 16 + lk * 4 + r)) v = -1e30f;
                s[n][r] = v;
            }

        // --- row max (per q-row, across 16 lanes) ---
        float pm[4];
#pragma unroll
        for (int r = 0; r < 4; ++r)
            pm[r] = fmaxf(fmaxf(s[0][r], s[1][r]), fmaxf(s[2][r], s[3][r]));
#pragma unroll
        for (int o = 1; o < 16; o <<= 1)
#pragma unroll
            for (int r = 0; r < 4; ++r)
                pm[r] = fmaxf(pm[r], __shfl_xor(pm[r], o, 16));

        float resc[4], rs[4];
#pragma unroll
        for (int r = 0; r < 4; ++r) {
            float mn = fmaxf(m_i[r], pm[r]);
            resc[r] = __expf(m_i[r] - mn);
            m_i[r] = mn;
            rs[r] = 0.f;
        }
        // --- P = exp(S - m), row sums ---
#pragma unroll
        for (int n = 0; n < 4; ++n)
#pragma unroll
            for (int r = 0; r < 4; ++r) {
                float p = __expf(s[n][r] - m_i[r]);
                s[n][r] = p;
                rs[r] += p;
            }
#pragma unroll
        for (int o = 1; o < 16; o <<= 1)
#pragma unroll
            for (int r = 0; r < 4; ++r)
                rs[r] += __shfl_xor(rs[r], o, 16);
#pragma unroll
        for (int r = 0; r < 4; ++r)
            l_i[r] = l_i[r] * resc[r] + rs[r];
#pragma unroll
        for (int n = 0; n < 8; ++n)
#pragma unroll
            for (int r = 0; r < 4; ++r)
                acc[n][r] *= resc[r];

        // --- P -> LDS (bf16, padded stride 72) ---
#pragma unroll
        for (int n = 0; n < 4; ++n)
#pragma unroll
            for (int r = 0; r < 4; ++r)
                Pw[(lk * 4 + r) * 72 + n * 16 + lr] = f2bf(s[n][r]);

        // --- Y += P V ---
#pragma unroll
        for (int ks = 0; ks < 2; ++ks) {
            short8 pf = *(const short8*)&Pw[lr * 72 + ks * 32 + lk * 8];
#pragma unroll
            for (int n8 = 0; n8 < 8; ++n8) {
                short8 vf = *(const short8*)&Vt[(n8 * 16 + lr) * 64 + ks * 32 + lk * 8];
                acc[n8] = __builtin_amdgcn_mfma_f32_16x16x32_bf16(pf, vf, acc[n8], 0, 0, 0);
            }
        }
        __syncthreads();
    }

    // --- finalize: Y / l, write bf16 ---
    unsigned short* yb = y + (size_t)(b * 1024) * 2048 + h * 128;
#pragma unroll
    for (int n8 = 0; n8 < 8; ++n8)
#pragma unroll
        for (int r = 0; r < 4; ++r) {
            int t = qt * 64 + w * 16 + lk * 4 + r;
            int d = n8 * 16 + lr;
            yb[(size_t)t * 2048 + d] = f2bf(acc[n8][r] / l_i[r]);
        }
}

// ============================================================
// host launch
// ============================================================
extern "C" void kernel_launch(void* const* d_in, const int* in_sizes, int n_in,
                              void* d_out, int out_size, void* d_ws, size_t ws_size,
                              hipStream_t stream) {
    const float* v_in  = (const float*)d_in[0];
    const float* xeps  = (const float*)d_in[1];
    const float* fcos  = (const float*)d_in[2];
    const float* fsin  = (const float*)d_in[3];
    const float* Wea   = (const float*)d_in[4];
    const float* Wa    = (const float*)d_in[5];
    const float* Wp    = (const float*)d_in[6];
    const float* Wep   = (const float*)d_in[7];
    float* out = (float*)d_out;

    // workspace layout (bf16 buffers)
    char* ws = (char*)d_ws;
    unsigned short* xe16 = (unsigned short*)ws;  ws += (size_t)MROWS * KDIM * 2;        // 16.8 MB
    unsigned short* v16  = (unsigned short*)ws;  ws += (size_t)MROWS * KDIM * 2;        // 16.8 MB
    unsigned short* WeaT = (unsigned short*)ws;  ws += (size_t)NQK * KDIM * 2;          // 16.8 MB
    unsigned short* WaT  = (unsigned short*)ws;  ws += (size_t)KDIM * KDIM * 2;         // 8.4 MB
    unsigned short* WpT  = (unsigned short*)ws;  ws += (size_t)KDIM * KDIM * 2;         // 8.4 MB
    unsigned short* WepT = (unsigned short*)ws;  ws += (size_t)KDIM * KDIM * 2;         // 8.4 MB
    unsigned short* qk16 = (unsigned short*)ws;  ws += (size_t)MROWS * NQK * 2;         // 33.6 MB
    unsigned short* vp16 = (unsigned short*)ws;  ws += (size_t)MROWS * KDIM * 2;        // 16.8 MB
    unsigned short* y16  = (unsigned short*)ws;  ws += (size_t)MROWS * KDIM * 2;        // 16.8 MB

    // 1. casts
    cast_f32_bf16<<<8192, 256, 0, stream>>>(xeps, xe16, MROWS * KDIM / 4);
    cast_f32_bf16<<<8192, 256, 0, stream>>>(v_in, v16,  MROWS * KDIM / 4);

    // 2. weight transpose-casts (K x N -> N x K)
    transpose_cast<<<dim3(NQK / 32, KDIM / 32), dim3(32, 8), 0, stream>>>(Wea, WeaT, KDIM, NQK);
    transpose_cast<<<dim3(KDIM / 32, KDIM / 32), dim3(32, 8), 0, stream>>>(Wa,  WaT,  KDIM, KDIM);
    transpose_cast<<<dim3(KDIM / 32, KDIM / 32), dim3(32, 8), 0, stream>>>(Wp,  WpT,  KDIM, KDIM);
    transpose_cast<<<dim3(KDIM / 32, KDIM / 32), dim3(32, 8), 0, stream>>>(Wep, WepT, KDIM, KDIM);

    // 3. qk = x_eps @ W_eps_attn   (bf16 out)
    gemm_bt<true><<<dim3(NQK / 128, MROWS / 128), 256, 0, stream>>>(
        xe16, WeaT, nullptr, qk16, MROWS, NQK, KDIM);

    // 4. RoPE in-place on q and k
    rope_kernel<<<8192, 256, 0, stream>>>(qk16, fcos, fsin);

    // 5. vp = v @ W_attn           (bf16 out)
    gemm_bt<true><<<dim3(KDIM / 128, MROWS / 128), 256, 0, stream>>>(
        v16, WaT, nullptr, vp16, MROWS, KDIM, KDIM);

    // 6. attention -> y16
    attn_kernel<<<dim3(16, 64), 256, 0, stream>>>(qk16, vp16, y16);

    // 7. v_out = y @ W_proj        (f32 out, first half of d_out)
    gemm_bt<false><<<dim3(KDIM / 128, MROWS / 128), 256, 0, stream>>>(
        y16, WpT, out, nullptr, MROWS, KDIM, KDIM);

    // 8. x_eps_out = x_eps @ W_eps_proj (f32 out, second half)
    gemm_bt<false><<<dim3(KDIM / 128, MROWS / 128), 256, 0, stream>>>(
        xe16, WepT, out + (size_t)MROWS * KDIM, nullptr, MROWS, KDIM, KDIM);
}

// Round 2
// 410.470 us; speedup vs baseline: 1.4043x; 1.4043x over previous
//
#include <hip/hip_runtime.h>
#include <stdint.h>

// ---------- types ----------
typedef __attribute__((ext_vector_type(8))) short  short8;   // 8 bf16 (4 VGPRs)
typedef __attribute__((ext_vector_type(4))) float  f32x4;
typedef __attribute__((ext_vector_type(4))) float  float4v;
typedef __attribute__((ext_vector_type(4))) unsigned short ushort4v;

#define DEV __device__ __forceinline__

// ---------- bf16 helpers (RNE) ----------
DEV unsigned short f2bf(float f) {
    union { float f; unsigned int u; } x; x.f = f;
    unsigned int u = x.u;
    unsigned int r = (u + 0x7fffu + ((u >> 16) & 1u)) >> 16;
    return (unsigned short)r;
}
DEV float bf2f(unsigned short b) {
    union { unsigned int u; float f; } x; x.u = ((unsigned int)b) << 16;
    return x.f;
}

// ---------- async global->LDS, 16B/lane ----------
DEV void gll16(const void* g, void* l) {
    __builtin_amdgcn_global_load_lds(
        (const __attribute__((address_space(1))) void*)g,
        (__attribute__((address_space(3))) void*)l, 16, 0, 0);
}

// ---------- problem constants ----------
// B=4 T=1024 DIM=2048 H=16 HD=HDE=128 ; M = B*T = 4096
#define MROWS 4096
#define KDIM  2048
#define NQK   4096

// ============================================================
// elementwise f32 -> bf16 cast
// ============================================================
__global__ void cast_f32_bf16(const float* __restrict__ in,
                              unsigned short* __restrict__ out, int n4) {
    int i = blockIdx.x * blockDim.x + threadIdx.x;
    if (i < n4) {
        float4v f = ((const float4v*)in)[i];
        ushort4v o;
        o[0] = f2bf(f[0]); o[1] = f2bf(f[1]); o[2] = f2bf(f[2]); o[3] = f2bf(f[3]);
        ((ushort4v*)out)[i] = o;
    }
}

// ============================================================
// transpose + cast: W (K x N, f32) -> Wt (N x K, bf16)
// ============================================================
__global__ void transpose_cast(const float* __restrict__ W,
                               unsigned short* __restrict__ Wt, int K, int N) {
    __shared__ float tile[32][33];
    int tx = threadIdx.x, ty = threadIdx.y;
    int n0 = blockIdx.x * 32, k0 = blockIdx.y * 32;
#pragma unroll
    for (int j = 0; j < 32; j += 8)
        tile[ty + j][tx] = W[(size_t)(k0 + ty + j) * N + n0 + tx];
    __syncthreads();
#pragma unroll
    for (int j = 0; j < 32; j += 8)
        Wt[(size_t)(n0 + ty + j) * K + k0 + tx] = f2bf(tile[tx][ty + j]);
}

// ============================================================
// bf16 transpose: vp [4096 t][2048 (h d)] -> vpT [64 bh][128 d][1024 t]
// grid (1024/32, 8192/32), block (32,8)
// ============================================================
__global__ void transpose_v(const unsigned short* __restrict__ vp,
                            unsigned short* __restrict__ vpT) {
    __shared__ unsigned short tile[32][34];   // stride 68B -> 17-word, conflict-free reads
    int tx = threadIdx.x, ty = threadIdx.y;
    int R0 = blockIdx.y * 32;                 // out row base = bh*128 + d0
    int c0 = blockIdx.x * 32;                 // t base
    int bh = R0 >> 7, d0 = R0 & 127;
    int b = bh >> 4, h = bh & 15;
#pragma unroll
    for (int j = 0; j < 32; j += 8)
        tile[ty + j][tx] = vp[(size_t)(b * 1024 + c0 + ty + j) * 2048 + h * 128 + d0 + tx];
    __syncthreads();
#pragma unroll
    for (int j = 0; j < 32; j += 8)
        vpT[(size_t)(R0 + ty + j) * 1024 + c0 + tx] = tile[tx][ty + j];
}

// ============================================================
// GEMM  C[M x N] = A[M x K] * Bt[N x K]^T   (bf16 in, f32 acc)
// 128x128 tile, 4 waves (2x2), BK=32  (m97 structure, unchanged)
// ============================================================
template <bool OUTBF>
__global__ __launch_bounds__(256) void gemm_bt(
    const unsigned short* __restrict__ A,
    const unsigned short* __restrict__ Bt,
    float* __restrict__ Cf, unsigned short* __restrict__ C16,
    int M, int N, int K) {

    __shared__ __align__(16) unsigned short As[128 * 32];
    __shared__ __align__(16) unsigned short Bs[128 * 32];

    const int tid  = threadIdx.x;
    const int w    = tid >> 6;
    const int lane = tid & 63;
    const int lr   = lane & 15;
    const int lk   = lane >> 4;
    const int wr   = w >> 1, wc = w & 1;
    const int rowBase = blockIdx.y * 128;
    const int colBase = blockIdx.x * 128;

    f32x4 acc[4][4];
#pragma unroll
    for (int m = 0; m < 4; ++m)
#pragma unroll
        for (int n = 0; n < 4; ++n)
            acc[m][n] = (f32x4){0.f, 0.f, 0.f, 0.f};

    for (int k0 = 0; k0 < K; k0 += 32) {
#pragma unroll
        for (int r = 0; r < 2; ++r) {
            int E   = r * 2048 + tid * 8;
            int row = E >> 5, col = E & 31;
            gll16(A  + (size_t)(rowBase + row) * K + k0 + col, &As[r * 2048 + w * 512]);
            gll16(Bt + (size_t)(colBase + row) * K + k0 + col, &Bs[r * 2048 + w * 512]);
        }
        __syncthreads();

        short8 a[4], b[4];
#pragma unroll
        for (int m = 0; m < 4; ++m)
            a[m] = *(const short8*)&As[(wr * 64 + m * 16 + lr) * 32 + lk * 8];
#pragma unroll
        for (int n = 0; n < 4; ++n)
            b[n] = *(const short8*)&Bs[(wc * 64 + n * 16 + lr) * 32 + lk * 8];
#pragma unroll
        for (int m = 0; m < 4; ++m)
#pragma unroll
            for (int n = 0; n < 4; ++n)
                acc[m][n] = __builtin_amdgcn_mfma_f32_16x16x32_bf16(a[m], b[n], acc[m][n], 0, 0, 0);
        __syncthreads();
    }

#pragma unroll
    for (int m = 0; m < 4; ++m)
#pragma unroll
        for (int n = 0; n < 4; ++n)
#pragma unroll
            for (int r = 0; r < 4; ++r) {
                int row = rowBase + wr * 64 + m * 16 + lk * 4 + r;
                int col = colBase + wc * 64 + n * 16 + lr;
                float v = acc[m][n][r];
                if (OUTBF) C16[(size_t)row * N + col] = f2bf(v);
                else       Cf [(size_t)row * N + col] = v;
            }
}

// ============================================================
// RoPE in-place on qk16 (4096 x 4096 bf16)
// ============================================================
__global__ void rope_kernel(unsigned short* __restrict__ qk,
                            const float* __restrict__ fcos,
                            const float* __restrict__ fsin) {
    int idx  = blockIdx.x * 256 + threadIdx.x;
    int row  = idx >> 9;
    int g    = idx & 511;
    int t    = row & 1023;
    int half = g >> 8;
    int hp   = g & 255;
    int h    = hp >> 4;
    int ig   = hp & 15;
    int col  = half * 2048 + h * 128 + ig * 8;
    size_t off = (size_t)row * 4096 + col;

    short8 v = *(short8*)(qk + off);
    int i0 = ig * 4;
    float4v c = *(const float4v*)(fcos + t * 64 + i0);
    float4v s = *(const float4v*)(fsin + t * 64 + i0);
    short8 o;
#pragma unroll
    for (int p = 0; p < 4; ++p) {
        float re = bf2f((unsigned short)v[2 * p]);
        float im = bf2f((unsigned short)v[2 * p + 1]);
        o[2 * p]     = (short)f2bf(re * c[p] - im * s[p]);
        o[2 * p + 1] = (short)f2bf(re * s[p] + im * c[p]);
    }
    *(short8*)(qk + off) = o;
}

// ============================================================
// Flash-style causal attention v2.
// grid = (64 bh, 8 q-blocks), block = 256 (4 waves x 32 q-rows = 128 rows).
// qt = 7 - blockIdx.y (heavy tiles dispatched first for load balance).
// K tile [64][128] and V^T tile [128][64] staged via global_load_lds with
// T2 XOR-swizzle (pre-swizzled global source + swizzled LDS reads).
// V comes pre-transposed from vpT[bh][d][t].
// ============================================================
__global__ __launch_bounds__(256) void attn_kernel(
    const unsigned short* __restrict__ qk,   // 4096 x 4096 (q | k), roped
    const unsigned short* __restrict__ vpT,  // [64 bh][128 d][1024 t]
    unsigned short* __restrict__ y) {        // 4096 x 2048

    const int bh = blockIdx.x;               // 0..63
    const int qt = 7 - (int)blockIdx.y;      // 0..7, heavy first
    const int b = bh >> 4, h = bh & 15;
    const int qb0 = qt * 128;

    __shared__ __align__(16) unsigned short Kt[64 * 128];   // [key][d], swizzled
    __shared__ __align__(16) unsigned short Vt[128 * 64];   // [d][k],  swizzled
    __shared__ __align__(16) unsigned short Pl[4 * 32 * 72];

    const int tid = threadIdx.x, w = tid >> 6, lane = tid & 63;
    const int lr = lane & 15, lk = lane >> 4;

    const unsigned short* Qb = qk + (size_t)(b * 1024) * 4096 + h * 128;
    const unsigned short* Kb = Qb + 2048;
    const unsigned short* Vg = vpT + (size_t)bh * 128 * 1024;
    unsigned short* Pw = &Pl[w * 32 * 72];

    // Q fragments: 2 m-frags x 4 k-chunks
    short8 qf[2][4];
#pragma unroll
    for (int m = 0; m < 2; ++m) {
        const unsigned short* qrow = Qb + (size_t)(qb0 + w * 32 + m * 16 + lr) * 4096;
#pragma unroll
        for (int db = 0; db < 4; ++db)
            qf[m][db] = *(const short8*)(qrow + db * 32 + lk * 8);
    }

    f32x4 acc[2][8];
#pragma unroll
    for (int m = 0; m < 2; ++m)
#pragma unroll
        for (int n = 0; n < 8; ++n) acc[m][n] = (f32x4){0.f, 0.f, 0.f, 0.f};
    float m_i[2][4], l_i[2][4];
#pragma unroll
    for (int m = 0; m < 2; ++m)
#pragma unroll
        for (int r = 0; r < 4; ++r) { m_i[m][r] = -1e30f; l_i[m][r] = 0.f; }

    const int nkt = 2 * qt + 2;
    for (int kt = 0; kt < nkt; ++kt) {
        // --- stage K tile: 64 rows x 256B, swizzled source ---
#pragma unroll
        for (int c = 0; c < 4; ++c) {
            int base = w * 4096 + c * 1024;           // LDS byte base (wave-uniform)
            int row  = (base >> 8) + (lane >> 4);     // key within tile
            int colB = (lane & 15) * 16;
            int scol = colB ^ ((row & 7) << 4);
            gll16(Kb + (size_t)(kt * 64 + row) * 4096 + (scol >> 1),
                  (char*)Kt + base);
        }
        // --- stage V^T tile: 128 rows x 128B, swizzled source ---
#pragma unroll
        for (int c = 0; c < 4; ++c) {
            int base = w * 4096 + c * 1024;
            int d    = (base >> 7) + (lane >> 3);
            int colB = (lane & 7) * 16;
            int scol = colB ^ ((d & 7) << 4);
            gll16(Vg + (size_t)d * 1024 + kt * 64 + (scol >> 1),
                  (char*)Vt + base);
        }
        __syncthreads();

        // --- S = Q K^T : per wave 32 q-rows x 64 keys ---
        f32x4 s[2][4];
#pragma unroll
        for (int m = 0; m < 2; ++m)
#pragma unroll
            for (int n = 0; n < 4; ++n) s[m][n] = (f32x4){0.f, 0.f, 0.f, 0.f};
#pragma unroll
        for (int db = 0; db < 4; ++db)
#pragma unroll
            for (int n = 0; n < 4; ++n) {
                int krow = n * 16 + lr;
                int cb = (db * 64 + lk * 16) ^ ((krow & 7) << 4);
                short8 kf = *(const short8*)((const char*)Kt + krow * 256 + cb);
                s[0][n] = __builtin_amdgcn_mfma_f32_16x16x32_bf16(qf[0][db], kf, s[0][n], 0, 0, 0);
                s[1][n] = __builtin_amdgcn_mfma_f32_16x16x32_bf16(qf[1][db], kf, s[1][n], 0, 0, 0);
            }

        // --- scale + causal mask (only diagonal tiles need it) ---
        const float sc = 0.08838834764831845f;   // 1/sqrt(128)
        const bool diag = (kt >= 2 * qt);
#pragma unroll
        for (int m = 0; m < 2; ++m)
#pragma unroll
            for (int n = 0; n < 4; ++n)
#pragma unroll
                for (int r = 0; r < 4; ++r) {
                    float v = s[m][n][r] * sc;
                    if (diag) {
                        int q   = qb0 + w * 32 + m * 16 + lk * 4 + r;
                        int key = kt * 64 + n * 16 + lr;
                        if (key > q) v = -1e30f;
                    }
                    s[m][n][r] = v;
                }

        // --- online softmax per m-frag ---
#pragma unroll
        for (int m = 0; m < 2; ++m) {
            float pm[4];
#pragma unroll
            for (int r = 0; r < 4; ++r)
                pm[r] = fmaxf(fmaxf(s[m][0][r], s[m][1][r]), fmaxf(s[m][2][r], s[m][3][r]));
#pragma unroll
            for (int o = 1; o < 16; o <<= 1)
#pragma unroll
                for (int r = 0; r < 4; ++r)
                    pm[r] = fmaxf(pm[r], __shfl_xor(pm[r], o, 16));

            float resc[4], rs[4];
#pragma unroll
            for (int r = 0; r < 4; ++r) {
                float mn = fmaxf(m_i[m][r], pm[r]);
                resc[r] = __expf(m_i[m][r] - mn);
                m_i[m][r] = mn;
                rs[r] = 0.f;
            }
#pragma unroll
            for (int n = 0; n < 4; ++n)
#pragma unroll
                for (int r = 0; r < 4; ++r) {
                    float p = __expf(s[m][n][r] - m_i[m][r]);
                    s[m][n][r] = p;
                    rs[r] += p;
                }
#pragma unroll
            for (int o = 1; o < 16; o <<= 1)
#pragma unroll
                for (int r = 0; r < 4; ++r)
                    rs[r] += __shfl_xor(rs[r], o, 16);
#pragma unroll
            for (int r = 0; r < 4; ++r)
                l_i[m][r] = l_i[m][r] * resc[r] + rs[r];
#pragma unroll
            for (int n = 0; n < 8; ++n)
#pragma unroll
                for (int r = 0; r < 4; ++r)
                    acc[m][n][r] *= resc[r];

            // --- P -> LDS (bf16, padded stride 72) ---
#pragma unroll
            for (int n = 0; n < 4; ++n)
#pragma unroll
                for (int r = 0; r < 4; ++r)
                    Pw[(m * 16 + lk * 4 + r) * 72 + n * 16 + lr] = f2bf(s[m][n][r]);
        }

        // --- Y += P V ---
#pragma unroll
        for (int ks = 0; ks < 2; ++ks) {
            short8 pf0 = *(const short8*)&Pw[(lr) * 72 + ks * 32 + lk * 8];
            short8 pf1 = *(const short8*)&Pw[(16 + lr) * 72 + ks * 32 + lk * 8];
#pragma unroll
            for (int n8 = 0; n8 < 8; ++n8) {
                int d  = n8 * 16 + lr;
                int cb = (ks * 64 + lk * 16) ^ ((d & 7) << 4);
                short8 vf = *(const short8*)((const char*)Vt + d * 128 + cb);
                acc[0][n8] = __builtin_amdgcn_mfma_f32_16x16x32_bf16(pf0, vf, acc[0][n8], 0, 0, 0);
                acc[1][n8] = __builtin_amdgcn_mfma_f32_16x16x32_bf16(pf1, vf, acc[1][n8], 0, 0, 0);
            }
        }
        __syncthreads();
    }

    // --- finalize ---
    unsigned short* yb = y + (size_t)(b * 1024) * 2048 + h * 128;
#pragma unroll
    for (int m = 0; m < 2; ++m)
#pragma unroll
        for (int n8 = 0; n8 < 8; ++n8)
#pragma unroll
            for (int r = 0; r < 4; ++r) {
                int t = qb0 + w * 32 + m * 16 + lk * 4 + r;
                int d = n8 * 16 + lr;
                yb[(size_t)t * 2048 + d] = f2bf(acc[m][n8][r] / l_i[m][r]);
            }
}

// ============================================================
// host launch
// ============================================================
extern "C" void kernel_launch(void* const* d_in, const int* in_sizes, int n_in,
                              void* d_out, int out_size, void* d_ws, size_t ws_size,
                              hipStream_t stream) {
    const float* v_in  = (const float*)d_in[0];
    const float* xeps  = (const float*)d_in[1];
    const float* fcos  = (const float*)d_in[2];
    const float* fsin  = (const float*)d_in[3];
    const float* Wea   = (const float*)d_in[4];
    const float* Wa    = (const float*)d_in[5];
    const float* Wp    = (const float*)d_in[6];
    const float* Wep   = (const float*)d_in[7];
    float* out = (float*)d_out;

    // workspace layout (bf16 buffers)
    char* ws = (char*)d_ws;
    unsigned short* xe16 = (unsigned short*)ws;  ws += (size_t)MROWS * KDIM * 2;
    unsigned short* v16  = (unsigned short*)ws;  ws += (size_t)MROWS * KDIM * 2;
    unsigned short* WeaT = (unsigned short*)ws;  ws += (size_t)NQK * KDIM * 2;
    unsigned short* WaT  = (unsigned short*)ws;  ws += (size_t)KDIM * KDIM * 2;
    unsigned short* WpT  = (unsigned short*)ws;  ws += (size_t)KDIM * KDIM * 2;
    unsigned short* WepT = (unsigned short*)ws;  ws += (size_t)KDIM * KDIM * 2;
    unsigned short* qk16 = (unsigned short*)ws;  ws += (size_t)MROWS * NQK * 2;
    unsigned short* vp16 = (unsigned short*)ws;  ws += (size_t)MROWS * KDIM * 2;
    unsigned short* y16  = (unsigned short*)ws;  ws += (size_t)MROWS * KDIM * 2;
    unsigned short* vpT  = v16;   // v16 is dead after the vp GEMM; reuse its slot

    // 1. casts
    cast_f32_bf16<<<8192, 256, 0, stream>>>(xeps, xe16, MROWS * KDIM / 4);
    cast_f32_bf16<<<8192, 256, 0, stream>>>(v_in, v16,  MROWS * KDIM / 4);

    // 2. weight transpose-casts (K x N -> N x K)
    transpose_cast<<<dim3(NQK / 32, KDIM / 32), dim3(32, 8), 0, stream>>>(Wea, WeaT, KDIM, NQK);
    transpose_cast<<<dim3(KDIM / 32, KDIM / 32), dim3(32, 8), 0, stream>>>(Wa,  WaT,  KDIM, KDIM);
    transpose_cast<<<dim3(KDIM / 32, KDIM / 32), dim3(32, 8), 0, stream>>>(Wp,  WpT,  KDIM, KDIM);
    transpose_cast<<<dim3(KDIM / 32, KDIM / 32), dim3(32, 8), 0, stream>>>(Wep, WepT, KDIM, KDIM);

    // 3. qk = x_eps @ W_eps_attn   (bf16 out)
    gemm_bt<true><<<dim3(NQK / 128, MROWS / 128), 256, 0, stream>>>(
        xe16, WeaT, nullptr, qk16, MROWS, NQK, KDIM);

    // 4. RoPE in-place on q and k
    rope_kernel<<<8192, 256, 0, stream>>>(qk16, fcos, fsin);

    // 5. vp = v @ W_attn           (bf16 out)
    gemm_bt<true><<<dim3(KDIM / 128, MROWS / 128), 256, 0, stream>>>(
        v16, WaT, nullptr, vp16, MROWS, KDIM, KDIM);

    // 5b. transpose vp -> vpT [bh][d][t]   (v16 buffer reused)
    transpose_v<<<dim3(1024 / 32, 8192 / 32), dim3(32, 8), 0, stream>>>(vp16, vpT);

    // 6. attention -> y16  (heavy q-tiles first)
    attn_kernel<<<dim3(64, 8), 256, 0, stream>>>(qk16, vpT, y16);

    // 7. v_out = y @ W_proj        (f32 out, first half of d_out)
    gemm_bt<false><<<dim3(KDIM / 128, MROWS / 128), 256, 0, stream>>>(
        y16, WpT, out, nullptr, MROWS, KDIM, KDIM);

    // 8. x_eps_out = x_eps @ W_eps_proj (f32 out, second half)
    gemm_bt<false><<<dim3(KDIM / 128, MROWS / 128), 256, 0, stream>>>(
        xe16, WepT, out + (size_t)MROWS * KDIM, nullptr, MROWS, KDIM, KDIM);
}

// Round 3
// 327.388 us; speedup vs baseline: 1.7607x; 1.2538x over previous
//
#include <hip/hip_runtime.h>
#include <stdint.h>

// ---------- types ----------
typedef __attribute__((ext_vector_type(8))) short  short8;   // 8 bf16 (4 VGPRs)
typedef __attribute__((ext_vector_type(4))) float  f32x4;
typedef __attribute__((ext_vector_type(4))) float  float4v;
typedef __attribute__((ext_vector_type(4))) unsigned short ushort4v;

#define DEV __device__ __forceinline__

// ---------- bf16 helpers (RNE) ----------
DEV unsigned short f2bf(float f) {
    union { float f; unsigned int u; } x; x.f = f;
    unsigned int u = x.u;
    unsigned int r = (u + 0x7fffu + ((u >> 16) & 1u)) >> 16;
    return (unsigned short)r;
}
DEV float bf2f(unsigned short b) {
    union { unsigned int u; float f; } x; x.u = ((unsigned int)b) << 16;
    return x.f;
}

// ---------- async global->LDS, 16B/lane ----------
DEV void gll16(const void* g, void* l) {
    __builtin_amdgcn_global_load_lds(
        (const __attribute__((address_space(1))) void*)g,
        (__attribute__((address_space(3))) void*)l, 16, 0, 0);
}

// ---------- problem constants ----------
#define MROWS 4096
#define KDIM  2048
#define NQK   4096

// ============================================================
// elementwise f32 -> bf16 cast
// ============================================================
__global__ void cast_f32_bf16(const float* __restrict__ in,
                              unsigned short* __restrict__ out, int n4) {
    int i = blockIdx.x * blockDim.x + threadIdx.x;
    if (i < n4) {
        float4v f = ((const float4v*)in)[i];
        ushort4v o;
        o[0] = f2bf(f[0]); o[1] = f2bf(f[1]); o[2] = f2bf(f[2]); o[3] = f2bf(f[3]);
        ((ushort4v*)out)[i] = o;
    }
}

// ============================================================
// transpose + cast: W (K x N, f32) -> Wt (N x K, bf16)
// ============================================================
__global__ void transpose_cast(const float* __restrict__ W,
                               unsigned short* __restrict__ Wt, int K, int N) {
    __shared__ float tile[32][33];
    int tx = threadIdx.x, ty = threadIdx.y;
    int n0 = blockIdx.x * 32, k0 = blockIdx.y * 32;
#pragma unroll
    for (int j = 0; j < 32; j += 8)
        tile[ty + j][tx] = W[(size_t)(k0 + ty + j) * N + n0 + tx];
    __syncthreads();
#pragma unroll
    for (int j = 0; j < 32; j += 8)
        Wt[(size_t)(n0 + ty + j) * K + k0 + tx] = f2bf(tile[tx][ty + j]);
}

// ============================================================
// bf16 transpose: vp [4096 t][2048 (h d)] -> vpT [64 bh][128 d][1024 t]
// ============================================================
__global__ void transpose_v(const unsigned short* __restrict__ vp,
                            unsigned short* __restrict__ vpT) {
    __shared__ unsigned short tile[32][34];
    int tx = threadIdx.x, ty = threadIdx.y;
    int R0 = blockIdx.y * 32;
    int c0 = blockIdx.x * 32;
    int bh = R0 >> 7, d0 = R0 & 127;
    int b = bh >> 4, h = bh & 15;
#pragma unroll
    for (int j = 0; j < 32; j += 8)
        tile[ty + j][tx] = vp[(size_t)(b * 1024 + c0 + ty + j) * 2048 + h * 128 + d0 + tx];
    __syncthreads();
#pragma unroll
    for (int j = 0; j < 32; j += 8)
        vpT[(size_t)(R0 + ty + j) * 1024 + c0 + tx] = tile[tx][ty + j];
}

// ============================================================
// 256x256-tile 8-phase GEMM (guide §5 template, derived waits).
//   C[M x N] = A[M x K] * Bt[N x K]^T, bf16 in, f32 acc.
// 512 threads = 8 waves (2 M x 4 N); per-wave 128x64 output.
// BK=64; LDS 128 KiB = 2 dbuf x (A 2x[2ks][128][32] + B same).
// Swizzle: chunk ^= (row&8)?2:0 (st_16x32), applied on global src
// (stage) and LDS read -- global_load_lds dest stays linear.
// Stage schedule while computing tile u:
//   q0: A-half0(u+1)  q1: A-half1(u+1)   (other buffer)
//   q2: B-half0(u+2)  q3: B-half1(u+2)   (same buffer, freed at q0)
// vmcnt(4) at q3 (the 2 newest B half-tiles stay in flight).
// Dual-descriptor: blocks < nb0 run GEMM 0, rest run GEMM 1.
// ============================================================
__global__ __launch_bounds__(512, 2) void gemm256(
    const unsigned short* __restrict__ A0g, const unsigned short* __restrict__ B0g,
    float* __restrict__ Cf0, unsigned short* __restrict__ Ch0,
    int N0, int tx0, int nb0, int outbf0,
    const unsigned short* __restrict__ A1g, const unsigned short* __restrict__ B1g,
    float* __restrict__ Cf1, unsigned short* __restrict__ Ch1,
    int N1, int tx1, int outbf1, int K) {

    __shared__ __align__(16) char lds[131072];

    int blk = blockIdx.x;
    const unsigned short* Ag; const unsigned short* Bg;
    float* Cf; unsigned short* Ch; int N, tx, outbf;
    if (blk < nb0) { Ag = A0g; Bg = B0g; Cf = Cf0; Ch = Ch0; N = N0; tx = tx0; outbf = outbf0; }
    else { blk -= nb0; Ag = A1g; Bg = B1g; Cf = Cf1; Ch = Ch1; N = N1; tx = tx1; outbf = outbf1; }
    const int bx = blk % tx, by = blk / tx;

    const int tid = threadIdx.x;
    const int lane = tid & 63;
    const int w  = tid >> 6;
    const int lr = lane & 15, lk = lane >> 4;
    const int wm = w >> 2, wn = w & 3;
    const int cswz16 = (lk ^ ((lr >> 3) << 1)) * 16;   // swizzled 16B-chunk offset

    const unsigned short* Arow = Ag + (size_t)(by * 256) * K;
    const unsigned short* Brow = Bg + (size_t)(bx * 256) * K;

    // stage one half-tile (128 rows x 64 cols) : 2 x gll16 per thread
    auto STAGE = [&](const unsigned short* srcHalf, int k0, char* ldsHalf) {
        int row  = tid >> 2;
        int clog = (tid & 3) ^ (((tid >> 5) & 1) << 1);   // inverse(=same) swizzle on source
        const unsigned short* g = srcHalf + (size_t)row * K + k0 + clog * 8;
        gll16(g,      ldsHalf + tid * 16);            // ks=0 panel
        gll16(g + 32, ldsHalf + 8192 + tid * 16);     // ks=1 panel
    };

    f32x4 acc[8][4];
#pragma unroll
    for (int m = 0; m < 8; ++m)
#pragma unroll
        for (int n = 0; n < 4; ++n) acc[m][n] = (f32x4){0.f, 0.f, 0.f, 0.f};

    const int NT = K >> 6;   // 32
    char* buf0 = lds;
    char* buf1 = lds + 65536;

    // ---- prologue: B(0), A(0), B(1); leave B(1) in flight ----
    STAGE(Brow,                   0, buf0 + 32768);
    STAGE(Brow + (size_t)128 * K, 0, buf0 + 32768 + 16384);
    STAGE(Arow,                   0, buf0);
    STAGE(Arow + (size_t)128 * K, 0, buf0 + 16384);
    STAGE(Brow,                  64, buf1 + 32768);
    STAGE(Brow + (size_t)128 * K, 64, buf1 + 32768 + 16384);
    asm volatile("s_waitcnt vmcnt(4)" ::: "memory");
    __builtin_amdgcn_s_barrier();

#define GPHASE(MF0, MF1, STAGE_STMT, TAIL_STMT)                                   \
    {                                                                             \
        short8 afr0[2], afr1[2];                                                  \
        afr0[0] = *(const short8*)(aBase +        (MF0 * 16 + lr) * 64 + cswz16); \
        afr0[1] = *(const short8*)(aBase + 8192 + (MF0 * 16 + lr) * 64 + cswz16); \
        afr1[0] = *(const short8*)(aBase +        (MF1 * 16 + lr) * 64 + cswz16); \
        afr1[1] = *(const short8*)(aBase + 8192 + (MF1 * 16 + lr) * 64 + cswz16); \
        STAGE_STMT;                                                               \
        __builtin_amdgcn_sched_barrier(0);                                        \
        __builtin_amdgcn_s_barrier();                                             \
        asm volatile("s_waitcnt lgkmcnt(0)" ::: "memory");                        \
        __builtin_amdgcn_sched_barrier(0);                                        \
        __builtin_amdgcn_s_setprio(1);                                            \
        _Pragma("unroll")                                                         \
        for (int ks = 0; ks < 2; ++ks)                                            \
            _Pragma("unroll")                                                     \
            for (int nf = 0; nf < 4; ++nf) {                                      \
                acc[MF0][nf] = __builtin_amdgcn_mfma_f32_16x16x32_bf16(           \
                    afr0[ks], bfr[nf][ks], acc[MF0][nf], 0, 0, 0);                \
                acc[MF1][nf] = __builtin_amdgcn_mfma_f32_16x16x32_bf16(           \
                    afr1[ks], bfr[nf][ks], acc[MF1][nf], 0, 0, 0);                \
            }                                                                     \
        __builtin_amdgcn_s_setprio(0);                                            \
        __builtin_amdgcn_sched_barrier(0);                                        \
        TAIL_STMT;                                                                \
        __builtin_amdgcn_s_barrier();                                             \
    }

    for (int u = 0; u < NT; ++u) {
        char* bufC = (u & 1) ? buf1 : buf0;
        char* bufN = (u & 1) ? buf0 : buf1;
        const char* aBase = bufC + wm * 16384;
        const char* bBase = bufC + 32768 + (wn >> 1) * 16384;
        const int bRow0 = (wn & 1) * 64;
        const bool stA = (u + 1 < NT), stB = (u + 2 < NT);

        // B fragments for the whole K-tile (reused by all 4 phases)
        short8 bfr[4][2];
#pragma unroll
        for (int nf = 0; nf < 4; ++nf) {
            bfr[nf][0] = *(const short8*)(bBase +        (bRow0 + nf * 16 + lr) * 64 + cswz16);
            bfr[nf][1] = *(const short8*)(bBase + 8192 + (bRow0 + nf * 16 + lr) * 64 + cswz16);
        }

        GPHASE(0, 1, { if (stA) STAGE(Arow,                   (u + 1) * 64, bufN); }, {})
        GPHASE(2, 3, { if (stA) STAGE(Arow + (size_t)128 * K, (u + 1) * 64, bufN + 16384); }, {})
        GPHASE(4, 5, { if (stB) STAGE(Brow,                   (u + 2) * 64, bufC + 32768); }, {})
        GPHASE(6, 7, { if (stB) STAGE(Brow + (size_t)128 * K, (u + 2) * 64, bufC + 32768 + 16384); },
               { if (stB) { asm volatile("s_waitcnt vmcnt(4)" ::: "memory"); }
                 else     { asm volatile("s_waitcnt vmcnt(0)" ::: "memory"); } })
    }
#undef GPHASE

    // ---- epilogue: C/D layout col = lane&15, row = (lane>>4)*4 + reg ----
    if (outbf) {
#pragma unroll
        for (int mf = 0; mf < 8; ++mf)
#pragma unroll
            for (int nf = 0; nf < 4; ++nf)
#pragma unroll
                for (int r = 0; r < 4; ++r) {
                    int row = by * 256 + wm * 128 + mf * 16 + lk * 4 + r;
                    int col = bx * 256 + wn * 64 + nf * 16 + lr;
                    Ch[(size_t)row * N + col] = f2bf(acc[mf][nf][r]);
                }
    } else {
#pragma unroll
        for (int mf = 0; mf < 8; ++mf)
#pragma unroll
            for (int nf = 0; nf < 4; ++nf)
#pragma unroll
                for (int r = 0; r < 4; ++r) {
                    int row = by * 256 + wm * 128 + mf * 16 + lk * 4 + r;
                    int col = bx * 256 + wn * 64 + nf * 16 + lr;
                    Cf[(size_t)row * N + col] = acc[mf][nf][r];
                }
    }
}

// ============================================================
// RoPE in-place on qk16 (4096 x 4096 bf16)
// ============================================================
__global__ void rope_kernel(unsigned short* __restrict__ qk,
                            const float* __restrict__ fcos,
                            const float* __restrict__ fsin) {
    int idx  = blockIdx.x * 256 + threadIdx.x;
    int row  = idx >> 9;
    int g    = idx & 511;
    int t    = row & 1023;
    int half = g >> 8;
    int hp   = g & 255;
    int h    = hp >> 4;
    int ig   = hp & 15;
    int col  = half * 2048 + h * 128 + ig * 8;
    size_t off = (size_t)row * 4096 + col;

    short8 v = *(short8*)(qk + off);
    int i0 = ig * 4;
    float4v c = *(const float4v*)(fcos + t * 64 + i0);
    float4v s = *(const float4v*)(fsin + t * 64 + i0);
    short8 o;
#pragma unroll
    for (int p = 0; p < 4; ++p) {
        float re = bf2f((unsigned short)v[2 * p]);
        float im = bf2f((unsigned short)v[2 * p + 1]);
        o[2 * p]     = (short)f2bf(re * c[p] - im * s[p]);
        o[2 * p + 1] = (short)f2bf(re * s[p] + im * c[p]);
    }
    *(short8*)(qk + off) = o;
}

// ============================================================
// Flash-style causal attention (unchanged from round 2)
// ============================================================
__global__ __launch_bounds__(256) void attn_kernel(
    const unsigned short* __restrict__ qk,
    const unsigned short* __restrict__ vpT,
    unsigned short* __restrict__ y) {

    const int bh = blockIdx.x;
    const int qt = 7 - (int)blockIdx.y;
    const int b = bh >> 4, h = bh & 15;
    const int qb0 = qt * 128;

    __shared__ __align__(16) unsigned short Kt[64 * 128];
    __shared__ __align__(16) unsigned short Vt[128 * 64];
    __shared__ __align__(16) unsigned short Pl[4 * 32 * 72];

    const int tid = threadIdx.x, w = tid >> 6, lane = tid & 63;
    const int lr = lane & 15, lk = lane >> 4;

    const unsigned short* Qb = qk + (size_t)(b * 1024) * 4096 + h * 128;
    const unsigned short* Kb = Qb + 2048;
    const unsigned short* Vg = vpT + (size_t)bh * 128 * 1024;
    unsigned short* Pw = &Pl[w * 32 * 72];

    short8 qf[2][4];
#pragma unroll
    for (int m = 0; m < 2; ++m) {
        const unsigned short* qrow = Qb + (size_t)(qb0 + w * 32 + m * 16 + lr) * 4096;
#pragma unroll
        for (int db = 0; db < 4; ++db)
            qf[m][db] = *(const short8*)(qrow + db * 32 + lk * 8);
    }

    f32x4 acc[2][8];
#pragma unroll
    for (int m = 0; m < 2; ++m)
#pragma unroll
        for (int n = 0; n < 8; ++n) acc[m][n] = (f32x4){0.f, 0.f, 0.f, 0.f};
    float m_i[2][4], l_i[2][4];
#pragma unroll
    for (int m = 0; m < 2; ++m)
#pragma unroll
        for (int r = 0; r < 4; ++r) { m_i[m][r] = -1e30f; l_i[m][r] = 0.f; }

    const int nkt = 2 * qt + 2;
    for (int kt = 0; kt < nkt; ++kt) {
#pragma unroll
        for (int c = 0; c < 4; ++c) {
            int base = w * 4096 + c * 1024;
            int row  = (base >> 8) + (lane >> 4);
            int colB = (lane & 15) * 16;
            int scol = colB ^ ((row & 7) << 4);
            gll16(Kb + (size_t)(kt * 64 + row) * 4096 + (scol >> 1),
                  (char*)Kt + base);
        }
#pragma unroll
        for (int c = 0; c < 4; ++c) {
            int base = w * 4096 + c * 1024;
            int d    = (base >> 7) + (lane >> 3);
            int colB = (lane & 7) * 16;
            int scol = colB ^ ((d & 7) << 4);
            gll16(Vg + (size_t)d * 1024 + kt * 64 + (scol >> 1),
                  (char*)Vt + base);
        }
        __syncthreads();

        f32x4 s[2][4];
#pragma unroll
        for (int m = 0; m < 2; ++m)
#pragma unroll
            for (int n = 0; n < 4; ++n) s[m][n] = (f32x4){0.f, 0.f, 0.f, 0.f};
#pragma unroll
        for (int db = 0; db < 4; ++db)
#pragma unroll
            for (int n = 0; n < 4; ++n) {
                int krow = n * 16 + lr;
                int cb = (db * 64 + lk * 16) ^ ((krow & 7) << 4);
                short8 kf = *(const short8*)((const char*)Kt + krow * 256 + cb);
                s[0][n] = __builtin_amdgcn_mfma_f32_16x16x32_bf16(qf[0][db], kf, s[0][n], 0, 0, 0);
                s[1][n] = __builtin_amdgcn_mfma_f32_16x16x32_bf16(qf[1][db], kf, s[1][n], 0, 0, 0);
            }

        const float sc = 0.08838834764831845f;
        const bool diag = (kt >= 2 * qt);
#pragma unroll
        for (int m = 0; m < 2; ++m)
#pragma unroll
            for (int n = 0; n < 4; ++n)
#pragma unroll
                for (int r = 0; r < 4; ++r) {
                    float v = s[m][n][r] * sc;
                    if (diag) {
                        int q   = qb0 + w * 32 + m * 16 + lk * 4 + r;
                        int key = kt * 64 + n * 16 + lr;
                        if (key > q) v = -1e30f;
                    }
                    s[m][n][r] = v;
                }

#pragma unroll
        for (int m = 0; m < 2; ++m) {
            float pm[4];
#pragma unroll
            for (int r = 0; r < 4; ++r)
                pm[r] = fmaxf(fmaxf(s[m][0][r], s[m][1][r]), fmaxf(s[m][2][r], s[m][3][r]));
#pragma unroll
            for (int o = 1; o < 16; o <<= 1)
#pragma unroll
                for (int r = 0; r < 4; ++r)
                    pm[r] = fmaxf(pm[r], __shfl_xor(pm[r], o, 16));

            float resc[4], rs[4];
#pragma unroll
            for (int r = 0; r < 4; ++r) {
                float mn = fmaxf(m_i[m][r], pm[r]);
                resc[r] = __expf(m_i[m][r] - mn);
                m_i[m][r] = mn;
                rs[r] = 0.f;
            }
#pragma unroll
            for (int n = 0; n < 4; ++n)
#pragma unroll
                for (int r = 0; r < 4; ++r) {
                    float p = __expf(s[m][n][r] - m_i[m][r]);
                    s[m][n][r] = p;
                    rs[r] += p;
                }
#pragma unroll
            for (int o = 1; o < 16; o <<= 1)
#pragma unroll
                for (int r = 0; r < 4; ++r)
                    rs[r] += __shfl_xor(rs[r], o, 16);
#pragma unroll
            for (int r = 0; r < 4; ++r)
                l_i[m][r] = l_i[m][r] * resc[r] + rs[r];
#pragma unroll
            for (int n = 0; n < 8; ++n)
#pragma unroll
                for (int r = 0; r < 4; ++r)
                    acc[m][n][r] *= resc[r];

#pragma unroll
            for (int n = 0; n < 4; ++n)
#pragma unroll
                for (int r = 0; r < 4; ++r)
                    Pw[(m * 16 + lk * 4 + r) * 72 + n * 16 + lr] = f2bf(s[m][n][r]);
        }

#pragma unroll
        for (int ks = 0; ks < 2; ++ks) {
            short8 pf0 = *(const short8*)&Pw[(lr) * 72 + ks * 32 + lk * 8];
            short8 pf1 = *(const short8*)&Pw[(16 + lr) * 72 + ks * 32 + lk * 8];
#pragma unroll
            for (int n8 = 0; n8 < 8; ++n8) {
                int d  = n8 * 16 + lr;
                int cb = (ks * 64 + lk * 16) ^ ((d & 7) << 4);
                short8 vf = *(const short8*)((const char*)Vt + d * 128 + cb);
                acc[0][n8] = __builtin_amdgcn_mfma_f32_16x16x32_bf16(pf0, vf, acc[0][n8], 0, 0, 0);
                acc[1][n8] = __builtin_amdgcn_mfma_f32_16x16x32_bf16(pf1, vf, acc[1][n8], 0, 0, 0);
            }
        }
        __syncthreads();
    }

    unsigned short* yb = y + (size_t)(b * 1024) * 2048 + h * 128;
#pragma unroll
    for (int m = 0; m < 2; ++m)
#pragma unroll
        for (int n8 = 0; n8 < 8; ++n8)
#pragma unroll
            for (int r = 0; r < 4; ++r) {
                int t = qb0 + w * 32 + m * 16 + lk * 4 + r;
                int d = n8 * 16 + lr;
                yb[(size_t)t * 2048 + d] = f2bf(acc[m][n8][r] / l_i[m][r]);
            }
}

// ============================================================
// host launch
// ============================================================
extern "C" void kernel_launch(void* const* d_in, const int* in_sizes, int n_in,
                              void* d_out, int out_size, void* d_ws, size_t ws_size,
                              hipStream_t stream) {
    const float* v_in  = (const float*)d_in[0];
    const float* xeps  = (const float*)d_in[1];
    const float* fcos  = (const float*)d_in[2];
    const float* fsin  = (const float*)d_in[3];
    const float* Wea   = (const float*)d_in[4];
    const float* Wa    = (const float*)d_in[5];
    const float* Wp    = (const float*)d_in[6];
    const float* Wep   = (const float*)d_in[7];
    float* out = (float*)d_out;

    char* ws = (char*)d_ws;
    unsigned short* xe16 = (unsigned short*)ws;  ws += (size_t)MROWS * KDIM * 2;
    unsigned short* v16  = (unsigned short*)ws;  ws += (size_t)MROWS * KDIM * 2;
    unsigned short* WeaT = (unsigned short*)ws;  ws += (size_t)NQK * KDIM * 2;
    unsigned short* WaT  = (unsigned short*)ws;  ws += (size_t)KDIM * KDIM * 2;
    unsigned short* WpT  = (unsigned short*)ws;  ws += (size_t)KDIM * KDIM * 2;
    unsigned short* WepT = (unsigned short*)ws;  ws += (size_t)KDIM * KDIM * 2;
    unsigned short* qk16 = (unsigned short*)ws;  ws += (size_t)MROWS * NQK * 2;
    unsigned short* vp16 = (unsigned short*)ws;  ws += (size_t)MROWS * KDIM * 2;
    unsigned short* y16  = (unsigned short*)ws;  ws += (size_t)MROWS * KDIM * 2;
    unsigned short* vpT  = v16;   // v16 dead after vp GEMM; reuse

    // 1. casts
    cast_f32_bf16<<<8192, 256, 0, stream>>>(xeps, xe16, MROWS * KDIM / 4);
    cast_f32_bf16<<<8192, 256, 0, stream>>>(v_in, v16,  MROWS * KDIM / 4);

    // 2. weight transpose-casts
    transpose_cast<<<dim3(NQK / 32, KDIM / 32), dim3(32, 8), 0, stream>>>(Wea, WeaT, KDIM, NQK);
    transpose_cast<<<dim3(KDIM / 32, KDIM / 32), dim3(32, 8), 0, stream>>>(Wa,  WaT,  KDIM, KDIM);
    transpose_cast<<<dim3(KDIM / 32, KDIM / 32), dim3(32, 8), 0, stream>>>(Wp,  WpT,  KDIM, KDIM);
    transpose_cast<<<dim3(KDIM / 32, KDIM / 32), dim3(32, 8), 0, stream>>>(Wep, WepT, KDIM, KDIM);

    // 3. qk = xe16 @ WeaT  (bf16 out) : 16x16 tiles = 256 blocks
    gemm256<<<256, 512, 0, stream>>>(
        xe16, WeaT, nullptr, qk16, NQK, 16, 256, 1,
        xe16, WeaT, nullptr, qk16, NQK, 16, 1, KDIM);

    // 4. RoPE
    rope_kernel<<<8192, 256, 0, stream>>>(qk16, fcos, fsin);

    // 5. grouped: vp = v16 @ WaT (bf16) + x_eps_out = xe16 @ WepT (f32)
    gemm256<<<256, 512, 0, stream>>>(
        v16,  WaT,  nullptr, vp16, KDIM, 8, 128, 1,
        xe16, WepT, out + (size_t)MROWS * KDIM, nullptr, KDIM, 8, 0, KDIM);

    // 5b. transpose vp -> vpT [bh][d][t]
    transpose_v<<<dim3(1024 / 32, 8192 / 32), dim3(32, 8), 0, stream>>>(vp16, vpT);

    // 6. attention -> y16
    attn_kernel<<<dim3(64, 8), 256, 0, stream>>>(qk16, vpT, y16);

    // 7. v_out = y16 @ WpT (f32 out)
    gemm256<<<128, 512, 0, stream>>>(
        y16, WpT, out, nullptr, KDIM, 8, 128, 0,
        y16, WpT, out, nullptr, KDIM, 8, 0, KDIM);
}